// Round 9
// baseline (258.122 us; speedup 1.0000x reference)
//
#include <hip/hip_runtime.h>
#include <math.h>

#define S_LEN 2048
#define NH 16
#define HD 64
#define DMODEL 1024
#define BATCH 4
#define M_TOT (BATCH * S_LEN)   // 8192

typedef __attribute__((ext_vector_type(8))) short bf16x8;
typedef __attribute__((ext_vector_type(4))) float f32x4;

#define CK 0.18033688f   // (1/sqrt(64)) * log2(e), folded into Q at projection

__device__ __forceinline__ unsigned short f2bf_rne(float f) {
    unsigned u = __float_as_uint(f);
    u += 0x7fffu + ((u >> 16) & 1u);
    return (unsigned short)(u >> 16);
}

__device__ __forceinline__ void gld16(unsigned short* lds, const unsigned short* g) {
    __builtin_amdgcn_global_load_lds(
        (const __attribute__((address_space(1))) void*)g,
        (__attribute__((address_space(3))) void*)lds, 16, 0, 0);
}

// ---------------------------------------------------------------------------
// cvt_fused: one dispatch for all input conversion.
// z=0..2: Wq/Wk/Wv [k][n] fp32 -> WT [n][k] bf16 (64x64 transpose tiles)
// z=3:    Wf (1024x64) -> WfT [64][1024]   (only blockIdx.x==0 active)
// z=4:    x fp32 -> bf16 (256 blocks x 32 float4/thread)
// ---------------------------------------------------------------------------
__global__ __launch_bounds__(256) void cvt_fused(
    const float* __restrict__ x,
    const float* __restrict__ Wq, const float* __restrict__ Wk,
    const float* __restrict__ Wv, const float* __restrict__ Wf,
    unsigned short* __restrict__ xb, unsigned short* __restrict__ WT)
{
    const int z = blockIdx.z;
    const int tid = threadIdx.x;

    if (z < 4) {
        if (z == 3 && blockIdx.x > 0) return;
        const float* W = (z == 0) ? Wq : (z == 1) ? Wk : (z == 2) ? Wv : Wf;
        const int ncol = (z == 3) ? 64 : DMODEL;
        unsigned short* out = WT + (size_t)z * DMODEL * DMODEL;

        __shared__ float Lt[64][65];
        const int r0 = blockIdx.y * 64;
        const int c0 = blockIdx.x * 64;

        #pragma unroll
        for (int p = 0; p < 4; p++) {
            int row = (tid >> 4) + p * 16;
            int c4 = (tid & 15) * 4;
            float4 v = *(const float4*)(W + (size_t)(r0 + row) * ncol + c0 + c4);
            Lt[row][c4 + 0] = v.x; Lt[row][c4 + 1] = v.y;
            Lt[row][c4 + 2] = v.z; Lt[row][c4 + 3] = v.w;
        }
        __syncthreads();
        #pragma unroll
        for (int p = 0; p < 4; p++) {
            int nr = (tid >> 4) + p * 16;
            int kc = (tid & 15) * 4;
            unsigned short t[4];
            #pragma unroll
            for (int j = 0; j < 4; j++) t[j] = f2bf_rne(Lt[kc + j][nr]);
            *(uint2*)(out + (size_t)(c0 + nr) * DMODEL + r0 + kc) = *(uint2*)t;
        }
    } else {
        const int gtid = (blockIdx.y * 16 + blockIdx.x) * 256 + tid;
        #pragma unroll
        for (int it = 0; it < 8; it++) {
            #pragma unroll
            for (int k = 0; k < 4; k++) {
                size_t i = ((size_t)((it * 4 + k) * 65536) + gtid) * 4;
                float4 v = *(const float4*)(x + i);
                unsigned short t[4];
                t[0] = f2bf_rne(v.x); t[1] = f2bf_rne(v.y);
                t[2] = f2bf_rne(v.z); t[3] = f2bf_rne(v.w);
                *(uint2*)(xb + i) = *(uint2*)t;
            }
        }
    }
}

// ---------------------------------------------------------------------------
// Kernel 1 (R20/R8, FROZEN): FUSED QKV, x in regs (2-deep), W in LDS
// 3-buffer ring, counted vmcnt + raw s_barrier.  85.4 us measured.
// Six schedule interventions (R1,R2,R5,R6,R7,R8) moved 90->85; the only
// big lever was z-fusion (R3).  Frozen at best-measured config.
// ---------------------------------------------------------------------------
__global__ __launch_bounds__(512) void qkv_fused_mfma(
    const unsigned short* __restrict__ xb,
    const unsigned short* __restrict__ WT,
    const float* __restrict__ bq, const float* __restrict__ bk,
    const float* __restrict__ bv,
    unsigned short* __restrict__ Qb, unsigned short* __restrict__ Kb,
    unsigned short* __restrict__ Vtb)
{
    __shared__ __align__(16) unsigned short Ws[3][24 * 512];   // 72 KB

    const int lin = blockIdx.x;          // 0..511
    const int xcd = lin & 7;
    const int s   = lin >> 3;            // 0..63
    const int rb  = xcd * 4 + (s & 3);   // 0..31  (256-row tiles)
    const int ocb = s >> 2;              // 0..15  (64-oc tiles)

    const int tid = threadIdx.x;
    const int lane = tid & 63, w = tid >> 6;        // w 0..7
    const int quad = lane >> 4, l15 = lane & 15;

    const int R0  = rb * 256;
    const int OC0 = ocb * 64;

    const unsigned short* gW0 = WT +
        (size_t)(OC0 + (w >> 1) * 16 + l15) * DMODEL + (w & 1) * 32 + quad * 8;
    const unsigned short* gW1 = gW0 + (size_t)DMODEL * DMODEL;
    const unsigned short* gW2 = gW1 + (size_t)DMODEL * DMODEL;
    const unsigned short* gx0 = xb +
        (size_t)(R0 + w * 32 + l15) * DMODEL + quad * 8;
    const unsigned short* gx1 = gx0 + (size_t)16 * DMODEL;

    f32x4 acc[3][4][2];
    #pragma unroll
    for (int z = 0; z < 3; z++)
        #pragma unroll
        for (int i = 0; i < 4; i++)
            #pragma unroll
            for (int j = 0; j < 2; j++)
                #pragma unroll
                for (int c = 0; c < 4; c++) acc[z][i][j][c] = 0.f;

#define QKV_STAGEW(BUF, K)  do {                                       \
        gld16(Ws[BUF] + (0 * 8 + w) * 512, gW0 + (K));                 \
        gld16(Ws[BUF] + (1 * 8 + w) * 512, gW1 + (K));                 \
        gld16(Ws[BUF] + (2 * 8 + w) * 512, gW2 + (K));                 \
    } while (0)

#define QKV_LOADX(XF, K)  do {                                         \
        XF[0][0] = *(const bf16x8*)(gx0 + (K));                        \
        XF[0][1] = *(const bf16x8*)(gx0 + (K) + 32);                   \
        XF[1][0] = *(const bf16x8*)(gx1 + (K));                        \
        XF[1][1] = *(const bf16x8*)(gx1 + (K) + 32);                   \
    } while (0)

#define QKV_COMPUTE(BUF, XF)  do {                                     \
        _Pragma("unroll")                                              \
        for (int sl = 0; sl < 2; sl++) {                               \
            _Pragma("unroll")                                          \
            for (int z = 0; z < 3; z++) {                              \
                bf16x8 af[4];                                          \
                _Pragma("unroll")                                      \
                for (int i = 0; i < 4; i++)                            \
                    af[i] = *(const bf16x8*)&Ws[BUF][(z * 8 + i * 2 + sl) * 512 + lane * 8]; \
                if (z != 2) {                                          \
                    _Pragma("unroll")                                  \
                    for (int i = 0; i < 4; i++)                        \
                        _Pragma("unroll")                              \
                        for (int j = 0; j < 2; j++)                    \
                            acc[z][i][j] = __builtin_amdgcn_mfma_f32_16x16x32_bf16( \
                                af[i], XF[j][sl], acc[z][i][j], 0, 0, 0); \
                } else {                                               \
                    _Pragma("unroll")                                  \
                    for (int i = 0; i < 4; i++)                        \
                        _Pragma("unroll")                              \
                        for (int j = 0; j < 2; j++)                    \
                            acc[2][i][j] = __builtin_amdgcn_mfma_f32_16x16x32_bf16( \
                                XF[j][sl], af[i], acc[2][i][j], 0, 0, 0); \
                }                                                      \
            }                                                          \
        }                                                              \
    } while (0)

    bf16x8 xA[2][2], xB[2][2];

    QKV_STAGEW(0, 0);
    QKV_LOADX(xA, 0);
    QKV_STAGEW(1, 64);

    int b0 = 0;
    #pragma unroll 1
    for (int tt = 0; tt < 16; tt += 2) {
        const int b1 = (b0 + 1 == 3) ? 0 : b0 + 1;
        const int b2 = (b1 + 1 == 3) ? 0 : b1 + 1;

        asm volatile("s_waitcnt vmcnt(3)" ::: "memory");
        __builtin_amdgcn_s_barrier();
        if (tt < 15) QKV_LOADX(xB, (tt + 1) * 64);
        if (tt < 14) QKV_STAGEW(b2, (tt + 2) * 64);
        QKV_COMPUTE(b0, xA);

        if (tt < 14) asm volatile("s_waitcnt vmcnt(3)" ::: "memory");
        else         asm volatile("s_waitcnt vmcnt(0)" ::: "memory");
        __builtin_amdgcn_s_barrier();
        if (tt < 14) QKV_LOADX(xA, (tt + 2) * 64);
        if (tt < 13) QKV_STAGEW(b0, (tt + 3) * 64);
        QKV_COMPUTE(b1, xB);

        b0 = b2;
    }
#undef QKV_STAGEW
#undef QKV_LOADX
#undef QKV_COMPUTE

    #pragma unroll
    for (int z = 0; z < 2; z++) {
        unsigned short* out = (z == 0) ? Qb : Kb;
        const float* bias = (z == 0) ? bq : bk;
        const float qs = (z == 0) ? CK : 1.0f;
        #pragma unroll
        for (int i = 0; i < 4; i++) {
            int oc = OC0 + i * 16 + quad * 4;
            float4 bv4 = *(const float4*)&bias[oc];
            #pragma unroll
            for (int j = 0; j < 2; j++) {
                int row = R0 + w * 32 + j * 16 + l15;
                unsigned short t4[4];
                t4[0] = f2bf_rne((acc[z][i][j][0] + bv4.x) * qs);
                t4[1] = f2bf_rne((acc[z][i][j][1] + bv4.y) * qs);
                t4[2] = f2bf_rne((acc[z][i][j][2] + bv4.z) * qs);
                t4[3] = f2bf_rne((acc[z][i][j][3] + bv4.w) * qs);
                *(uint2*)(out + (size_t)row * DMODEL + oc) = *(uint2*)t4;
            }
        }
    }
    {
        const int b = R0 >> 11;
        const int sbase = (R0 & 2047) + w * 32;
        #pragma unroll
        for (int i = 0; i < 4; i++) {
            int oc = OC0 + i * 16 + l15;
            float bvv = bv[oc];
            #pragma unroll
            for (int j = 0; j < 2; j++) {
                int sq = sbase + j * 16 + quad * 4;
                unsigned short t4[4];
                t4[0] = f2bf_rne(acc[2][i][j][0] + bvv);
                t4[1] = f2bf_rne(acc[2][i][j][1] + bvv);
                t4[2] = f2bf_rne(acc[2][i][j][2] + bvv);
                t4[3] = f2bf_rne(acc[2][i][j][3] + bvv);
                *(uint2*)(Vtb + (size_t)(b * DMODEL + oc) * S_LEN + sq) = *(uint2*)t4;
            }
        }
    }
}

// ---------------------------------------------------------------------------
// Kernel 2 (R21): flash attention, q-tile 256 x KVBLK=256.
//   R8 state: attn ~83 us (just under top-5 cutoff), 16 steps x 2 full-drain
//   barriers with staging serialized between them.  KVBLK 128->256 halves
//   the barrier/drain events (8 steps) and doubles each compute phase --
//   the same fewer/larger-phases lever as R4's q-tile doubling (verified).
//   Staged bytes unchanged.  Per-r body byte-identical (r 0..7; Ks chunk
//   formula unchanged; Vs chunk dt*4+r -> dt*8+r).  Ps/lsum/O/epilogue
//   untouched.  LDS 48->80 KB = exactly 2 blocks/CU.  VGPR unchanged.
//   Staging roles: waves 0-3 stage K (8 gld16), waves 4-7 stage V (8).
// ---------------------------------------------------------------------------
__global__ __launch_bounds__(512, 4) void flash_attn_mfma(
    const unsigned short* __restrict__ Qg,   // [B*S,1024] bf16, pre-scaled by CK
    const unsigned short* __restrict__ Kg,   // [B*S,1024] bf16
    const unsigned short* __restrict__ Vtg,  // [B,H,64,S] bf16
    unsigned short* __restrict__ ctxb)       // [B*S,1024] bf16
{
    __shared__ __align__(16) unsigned short Ks[32 * 512];  // 32 KB
    __shared__ __align__(16) unsigned short Vs[32 * 512];  // 32 KB
    __shared__ __align__(16) unsigned short Ps[16 * 512];  // 16 KB

    const int tid  = threadIdx.x;
    const int lane = tid & 63, w = tid >> 6;   // w 0..7
    const int quad = lane >> 4, l15 = lane & 15;

    // ---- XCD swizzle: 512 blocks; all 8 q-blocks of (b,h) on XCD bh%8 ----
    const int lin = blockIdx.x;            // 0..511
    const int xcd = lin & 7;
    const int s   = lin >> 3;              // 0..63
    const int bh  = xcd + 8 * (s >> 3);    // 0..63, bh%8 == xcd
    const int qblk = s & 7;                // 0..7
    const int b = bh >> 4, h = bh & 15;
    const int r0 = qblk * 256;

    bf16x8 qf[2][2];
    #pragma unroll
    for (int nt = 0; nt < 2; nt++)
        #pragma unroll
        for (int ds = 0; ds < 2; ds++)
            qf[nt][ds] = *(const bf16x8*)(Qg +
                (size_t)(b * S_LEN + r0 + w * 32 + nt * 16 + l15) * DMODEL +
                h * HD + ds * 32 + quad * 8);

    // staging: waves 0-3 -> K rows [sw*64, sw*64+64); waves 4-7 -> V
    // d-groups [sw*16, sw*16+16) x 256 seq cols.  8 gld16 per wave per st.
    const int sw = w & 3;
    const unsigned short* gK = Kg +
        (size_t)(b * S_LEN + sw * 64 + l15) * DMODEL + h * HD + quad * 8;
    const unsigned short* gV = Vtg +
        ((size_t)(bh * HD + sw * 16 + l15)) * S_LEN + quad * 8;

    f32x4 O[2][4], lsum[2];
    #pragma unroll
    for (int rt = 0; rt < 2; rt++) {
        #pragma unroll
        for (int c = 0; c < 4; c++) lsum[rt][c] = 0.f;
        #pragma unroll
        for (int dt = 0; dt < 4; dt++)
            #pragma unroll
            for (int c = 0; c < 4; c++) O[rt][dt][c] = 0.f;
    }

    f32x4 zero4;
    #pragma unroll
    for (int c = 0; c < 4; c++) zero4[c] = 0.f;
    bf16x8 ones;
    #pragma unroll
    for (int c = 0; c < 8; c++) ones[c] = (short)0x3F80;   // bf16 1.0

    for (int st = 0; st < S_LEN / 256; st++) {   // 8 steps
        __syncthreads();
        if (w < 4) {
            // K chunks ((sw*4+m)*2 + half), m 0..3: rows sw*64+m*16+l15
            #pragma unroll
            for (int m = 0; m < 4; m++) {
                gld16(Ks + ((sw * 4 + m) * 2 + 0) * 512, gK + (size_t)(m * 16) * DMODEL);
                gld16(Ks + ((sw * 4 + m) * 2 + 1) * 512, gK + (size_t)(m * 16) * DMODEL + 32);
            }
            gK += (size_t)256 * DMODEL;
        } else {
            // V chunks (sw*8 + q), q 0..7: d = sw*16+l15, s = st*256+q*32
            #pragma unroll
            for (int q = 0; q < 8; q++)
                gld16(Vs + (sw * 8 + q) * 512, gV + q * 32);
            gV += 256;
        }
        __syncthreads();

        #pragma unroll
        for (int r = 0; r < 8; r++) {
            f32x4 sc[2][2];
            {
                bf16x8 kf0 = *(const bf16x8*)&Ks[((r * 2 + 0) * 2 + 0) * 512 + lane * 8];
                bf16x8 kf1 = *(const bf16x8*)&Ks[((r * 2 + 1) * 2 + 0) * 512 + lane * 8];
                sc[0][0] = __builtin_amdgcn_mfma_f32_16x16x32_bf16(kf0, qf[0][0], zero4, 0, 0, 0);
                sc[0][1] = __builtin_amdgcn_mfma_f32_16x16x32_bf16(kf0, qf[1][0], zero4, 0, 0, 0);
                sc[1][0] = __builtin_amdgcn_mfma_f32_16x16x32_bf16(kf1, qf[0][0], zero4, 0, 0, 0);
                sc[1][1] = __builtin_amdgcn_mfma_f32_16x16x32_bf16(kf1, qf[1][0], zero4, 0, 0, 0);
                kf0 = *(const bf16x8*)&Ks[((r * 2 + 0) * 2 + 1) * 512 + lane * 8];
                kf1 = *(const bf16x8*)&Ks[((r * 2 + 1) * 2 + 1) * 512 + lane * 8];
                sc[0][0] = __builtin_amdgcn_mfma_f32_16x16x32_bf16(kf0, qf[0][1], sc[0][0], 0, 0, 0);
                sc[0][1] = __builtin_amdgcn_mfma_f32_16x16x32_bf16(kf0, qf[1][1], sc[0][1], 0, 0, 0);
                sc[1][0] = __builtin_amdgcn_mfma_f32_16x16x32_bf16(kf1, qf[0][1], sc[1][0], 0, 0, 0);
                sc[1][1] = __builtin_amdgcn_mfma_f32_16x16x32_bf16(kf1, qf[1][1], sc[1][1], 0, 0, 0);
            }

            #pragma unroll
            for (int nt = 0; nt < 2; nt++) {
                #pragma unroll
                for (int mt = 0; mt < 2; mt++) {
                    unsigned u[4];
                    #pragma unroll
                    for (int c = 0; c < 4; c++)
                        u[c] = __float_as_uint(__builtin_amdgcn_exp2f(sc[mt][nt][c]));
                    uint2 pk;
                    pk.x = __builtin_amdgcn_perm(u[1], u[0], 0x07060302u);
                    pk.y = __builtin_amdgcn_perm(u[3], u[2], 0x07060302u);
                    int off = (w * 2 + nt) * 512 + (mt * 2 + (quad >> 1)) * 128 +
                              l15 * 8 + (quad & 1) * 4;
                    *(uint2*)&Ps[off] = pk;
                }
            }

            bf16x8 pf0 = *(const bf16x8*)&Ps[(w * 2 + 0) * 512 + lane * 8];
            bf16x8 pf1 = *(const bf16x8*)&Ps[(w * 2 + 1) * 512 + lane * 8];
            lsum[0] = __builtin_amdgcn_mfma_f32_16x16x32_bf16(pf0, ones, lsum[0], 0, 0, 0);
            lsum[1] = __builtin_amdgcn_mfma_f32_16x16x32_bf16(pf1, ones, lsum[1], 0, 0, 0);
            #pragma unroll
            for (int dt = 0; dt < 4; dt++) {
                bf16x8 vf = *(const bf16x8*)&Vs[(dt * 8 + r) * 512 + lane * 8];
                O[0][dt] = __builtin_amdgcn_mfma_f32_16x16x32_bf16(pf0, vf, O[0][dt], 0, 0, 0);
                O[1][dt] = __builtin_amdgcn_mfma_f32_16x16x32_bf16(pf1, vf, O[1][dt], 0, 0, 0);
            }
        }
    }

    const size_t srow = (size_t)(b * S_LEN + r0 + w * 32);
    #pragma unroll
    for (int rt = 0; rt < 2; rt++) {
        #pragma unroll
        for (int reg = 0; reg < 4; reg++) {
            float li = 1.0f / lsum[rt][reg];
            size_t rowoff = (srow + rt * 16 + quad * 4 + reg) * DMODEL + h * HD + l15;
            #pragma unroll
            for (int dt = 0; dt < 4; dt++)
                ctxb[rowoff + dt * 16] = f2bf_rne(O[rt][dt][reg] * li);
        }
    }
}

// ---------------------------------------------------------------------------
// Kernel 3: output projection v4, 8-way K-split.  512 blocks x 512 thr.
// ---------------------------------------------------------------------------
__global__ __launch_bounds__(512) void out_proj_mfma(
    const unsigned short* __restrict__ ctxb,
    const unsigned short* __restrict__ WfT,
    const float* __restrict__ bfb,
    float* __restrict__ out)
{
    __shared__ float Red[8 * 1024];   // [wave][lane][j*4+reg], 32 KB

    const int tid = threadIdx.x;
    const int lane = tid & 63, w = tid >> 6;    // w 0..7
    const int quad = lane >> 4, l15 = lane & 15;
    const int m0 = blockIdx.x * 16;

    const unsigned short* pA = ctxb + (size_t)(m0 + l15) * DMODEL + w * 128 + quad * 8;
    const unsigned short* pB = WfT + (size_t)l15 * DMODEL + w * 128 + quad * 8;

    f32x4 acc[4];
    #pragma unroll
    for (int j = 0; j < 4; j++)
        #pragma unroll
        for (int c = 0; c < 4; c++) acc[j][c] = 0.f;

    #pragma unroll
    for (int k0 = 0; k0 < 128; k0 += 32) {
        bf16x8 af = *(const bf16x8*)(pA + k0);
        #pragma unroll
        for (int j = 0; j < 4; j++) {
            bf16x8 bfr = *(const bf16x8*)(pB + (size_t)j * 16 * DMODEL + k0);
            acc[j] = __builtin_amdgcn_mfma_f32_16x16x32_bf16(af, bfr, acc[j], 0, 0, 0);
        }
    }

    #pragma unroll
    for (int j = 0; j < 4; j++)
        #pragma unroll
        for (int reg = 0; reg < 4; reg++)
            Red[w * 1024 + lane * 16 + j * 4 + reg] = acc[j][reg];
    __syncthreads();

    const int row = tid >> 5;          // 0..15
    const int c0  = (tid & 31) * 2;    // 0..62
    float2 o;
    float* op = &o.x;
    #pragma unroll
    for (int cc = 0; cc < 2; cc++) {
        int col = c0 + cc;
        int idx = ((row >> 2) * 16 + (col & 15)) * 16 + (col >> 4) * 4 + (row & 3);
        float s = 0.f;
        #pragma unroll
        for (int wv = 0; wv < 8; wv++) s += Red[wv * 1024 + idx];
        op[cc] = s + bfb[col];
    }
    *(float2*)(out + (size_t)(m0 + row) * HD + c0) = o;
}

// ---------------------------------------------------------------------------
extern "C" void kernel_launch(void* const* d_in, const int* in_sizes, int n_in,
                              void* d_out, int out_size, void* d_ws, size_t ws_size,
                              hipStream_t stream)
{
    (void)in_sizes; (void)n_in; (void)out_size; (void)ws_size;
    const float* x  = (const float*)d_in[0];
    const float* Wq = (const float*)d_in[1];
    const float* bq = (const float*)d_in[2];
    const float* Wk = (const float*)d_in[3];
    const float* bk = (const float*)d_in[4];
    const float* Wv = (const float*)d_in[5];
    const float* bv = (const float*)d_in[6];
    const float* Wf = (const float*)d_in[7];
    const float* bf = (const float*)d_in[8];
    float* out = (float*)d_out;

    char* wsb = (char*)d_ws;
    unsigned short* xb   = (unsigned short*)wsb;            // 16 MB, dead after qkv
    unsigned short* ctxb = (unsigned short*)wsb;            // reuses xb region
    unsigned short* WT   = xb + (size_t)M_TOT * DMODEL;     // 3x2 MB + WfT
    unsigned short* WfT  = WT + (size_t)3 * DMODEL * DMODEL;
    unsigned short* Qb   = (unsigned short*)(wsb + (size_t)32 * 1024 * 1024);
    unsigned short* Kb   = Qb + (size_t)M_TOT * DMODEL;
    unsigned short* Vtb  = Kb + (size_t)M_TOT * DMODEL;

    cvt_fused<<<dim3(16, 16, 5), 256, 0, stream>>>(x, Wq, Wk, Wv, Wf, xb, WT);
    qkv_fused_mfma<<<dim3(512), 512, 0, stream>>>(xb, WT, bq, bk, bv, Qb, Kb, Vtb);
    flash_attn_mfma<<<dim3(512), 512, 0, stream>>>(Qb, Kb, Vtb, ctxb);
    out_proj_mfma<<<dim3(M_TOT / 16), 512, 0, stream>>>(ctxb, WfT, bf, out);
}

// Round 11
// 256.100 us; speedup vs baseline: 1.0079x; 1.0079x over previous
//
#include <hip/hip_runtime.h>
#include <math.h>

#define S_LEN 2048
#define NH 16
#define HD 64
#define DMODEL 1024
#define BATCH 4
#define M_TOT (BATCH * S_LEN)   // 8192

typedef __attribute__((ext_vector_type(8))) short bf16x8;
typedef __attribute__((ext_vector_type(4))) float f32x4;

#define CK 0.18033688f   // (1/sqrt(64)) * log2(e), folded into Q at projection

__device__ __forceinline__ unsigned short f2bf_rne(float f) {
    unsigned u = __float_as_uint(f);
    u += 0x7fffu + ((u >> 16) & 1u);
    return (unsigned short)(u >> 16);
}

__device__ __forceinline__ void gld16(unsigned short* lds, const unsigned short* g) {
    __builtin_amdgcn_global_load_lds(
        (const __attribute__((address_space(1))) void*)g,
        (__attribute__((address_space(3))) void*)lds, 16, 0, 0);
}

// ---------------------------------------------------------------------------
// cvt_fused (R22): one dispatch for all input conversion.
// z=0..2: Wq/Wk/Wv [k][n] fp32 -> WT [n][k] bf16 (64x64 transpose tiles)
// z=3:    Wf (1024x64) -> WfT [64][1024]   (only blockIdx.x==0 active)
// z=4..7: x fp32 -> bf16, spread over 1024 blocks (was 256) -- the x-conv
//   was 48 MB on 1 block/CU = 4 waves/CU, latency-bound (R9 tail analysis:
//   cvt+out_proj+gaps ~ 86 us invariant).  4x blocks = 4x TLP, same work.
// ---------------------------------------------------------------------------
__global__ __launch_bounds__(256) void cvt_fused(
    const float* __restrict__ x,
    const float* __restrict__ Wq, const float* __restrict__ Wk,
    const float* __restrict__ Wv, const float* __restrict__ Wf,
    unsigned short* __restrict__ xb, unsigned short* __restrict__ WT)
{
    const int z = blockIdx.z;
    const int tid = threadIdx.x;

    if (z < 4) {
        if (z == 3 && blockIdx.x > 0) return;
        const float* W = (z == 0) ? Wq : (z == 1) ? Wk : (z == 2) ? Wv : Wf;
        const int ncol = (z == 3) ? 64 : DMODEL;
        unsigned short* out = WT + (size_t)z * DMODEL * DMODEL;

        __shared__ float Lt[64][65];
        const int r0 = blockIdx.y * 64;
        const int c0 = blockIdx.x * 64;

        #pragma unroll
        for (int p = 0; p < 4; p++) {
            int row = (tid >> 4) + p * 16;
            int c4 = (tid & 15) * 4;
            float4 v = *(const float4*)(W + (size_t)(r0 + row) * ncol + c0 + c4);
            Lt[row][c4 + 0] = v.x; Lt[row][c4 + 1] = v.y;
            Lt[row][c4 + 2] = v.z; Lt[row][c4 + 3] = v.w;
        }
        __syncthreads();
        #pragma unroll
        for (int p = 0; p < 4; p++) {
            int nr = (tid >> 4) + p * 16;
            int kc = (tid & 15) * 4;
            unsigned short t[4];
            #pragma unroll
            for (int j = 0; j < 4; j++) t[j] = f2bf_rne(Lt[kc + j][nr]);
            *(uint2*)(out + (size_t)(c0 + nr) * DMODEL + r0 + kc) = *(uint2*)t;
        }
    } else {
        const int zz = z - 4;   // 0..3
        const int gtid = (blockIdx.y * 16 + blockIdx.x) * 256 + tid;
        #pragma unroll
        for (int it = 0; it < 2; it++) {
            #pragma unroll
            for (int k = 0; k < 4; k++) {
                size_t i = ((size_t)((zz * 8 + it * 4 + k) * 65536) + gtid) * 4;
                float4 v = *(const float4*)(x + i);
                unsigned short t[4];
                t[0] = f2bf_rne(v.x); t[1] = f2bf_rne(v.y);
                t[2] = f2bf_rne(v.z); t[3] = f2bf_rne(v.w);
                *(uint2*)(xb + i) = *(uint2*)t;
            }
        }
    }
}

// ---------------------------------------------------------------------------
// Kernel 1 (R20/R8, FROZEN): FUSED QKV, x in regs (2-deep), W in LDS
// 3-buffer ring, counted vmcnt + raw s_barrier.  85.4 us measured.
// ---------------------------------------------------------------------------
__global__ __launch_bounds__(512) void qkv_fused_mfma(
    const unsigned short* __restrict__ xb,
    const unsigned short* __restrict__ WT,
    const float* __restrict__ bq, const float* __restrict__ bk,
    const float* __restrict__ bv,
    unsigned short* __restrict__ Qb, unsigned short* __restrict__ Kb,
    unsigned short* __restrict__ Vtb)
{
    __shared__ __align__(16) unsigned short Ws[3][24 * 512];   // 72 KB

    const int lin = blockIdx.x;          // 0..511
    const int xcd = lin & 7;
    const int s   = lin >> 3;            // 0..63
    const int rb  = xcd * 4 + (s & 3);   // 0..31  (256-row tiles)
    const int ocb = s >> 2;              // 0..15  (64-oc tiles)

    const int tid = threadIdx.x;
    const int lane = tid & 63, w = tid >> 6;        // w 0..7
    const int quad = lane >> 4, l15 = lane & 15;

    const int R0  = rb * 256;
    const int OC0 = ocb * 64;

    const unsigned short* gW0 = WT +
        (size_t)(OC0 + (w >> 1) * 16 + l15) * DMODEL + (w & 1) * 32 + quad * 8;
    const unsigned short* gW1 = gW0 + (size_t)DMODEL * DMODEL;
    const unsigned short* gW2 = gW1 + (size_t)DMODEL * DMODEL;
    const unsigned short* gx0 = xb +
        (size_t)(R0 + w * 32 + l15) * DMODEL + quad * 8;
    const unsigned short* gx1 = gx0 + (size_t)16 * DMODEL;

    f32x4 acc[3][4][2];
    #pragma unroll
    for (int z = 0; z < 3; z++)
        #pragma unroll
        for (int i = 0; i < 4; i++)
            #pragma unroll
            for (int j = 0; j < 2; j++)
                #pragma unroll
                for (int c = 0; c < 4; c++) acc[z][i][j][c] = 0.f;

#define QKV_STAGEW(BUF, K)  do {                                       \
        gld16(Ws[BUF] + (0 * 8 + w) * 512, gW0 + (K));                 \
        gld16(Ws[BUF] + (1 * 8 + w) * 512, gW1 + (K));                 \
        gld16(Ws[BUF] + (2 * 8 + w) * 512, gW2 + (K));                 \
    } while (0)

#define QKV_LOADX(XF, K)  do {                                         \
        XF[0][0] = *(const bf16x8*)(gx0 + (K));                        \
        XF[0][1] = *(const bf16x8*)(gx0 + (K) + 32);                   \
        XF[1][0] = *(const bf16x8*)(gx1 + (K));                        \
        XF[1][1] = *(const bf16x8*)(gx1 + (K) + 32);                   \
    } while (0)

#define QKV_COMPUTE(BUF, XF)  do {                                     \
        _Pragma("unroll")                                              \
        for (int sl = 0; sl < 2; sl++) {                               \
            _Pragma("unroll")                                          \
            for (int z = 0; z < 3; z++) {                              \
                bf16x8 af[4];                                          \
                _Pragma("unroll")                                      \
                for (int i = 0; i < 4; i++)                            \
                    af[i] = *(const bf16x8*)&Ws[BUF][(z * 8 + i * 2 + sl) * 512 + lane * 8]; \
                if (z != 2) {                                          \
                    _Pragma("unroll")                                  \
                    for (int i = 0; i < 4; i++)                        \
                        _Pragma("unroll")                              \
                        for (int j = 0; j < 2; j++)                    \
                            acc[z][i][j] = __builtin_amdgcn_mfma_f32_16x16x32_bf16( \
                                af[i], XF[j][sl], acc[z][i][j], 0, 0, 0); \
                } else {                                               \
                    _Pragma("unroll")                                  \
                    for (int i = 0; i < 4; i++)                        \
                        _Pragma("unroll")                              \
                        for (int j = 0; j < 2; j++)                    \
                            acc[2][i][j] = __builtin_amdgcn_mfma_f32_16x16x32_bf16( \
                                XF[j][sl], af[i], acc[2][i][j], 0, 0, 0); \
                }                                                      \
            }                                                          \
        }                                                              \
    } while (0)

    bf16x8 xA[2][2], xB[2][2];

    QKV_STAGEW(0, 0);
    QKV_LOADX(xA, 0);
    QKV_STAGEW(1, 64);

    int b0 = 0;
    #pragma unroll 1
    for (int tt = 0; tt < 16; tt += 2) {
        const int b1 = (b0 + 1 == 3) ? 0 : b0 + 1;
        const int b2 = (b1 + 1 == 3) ? 0 : b1 + 1;

        asm volatile("s_waitcnt vmcnt(3)" ::: "memory");
        __builtin_amdgcn_s_barrier();
        if (tt < 15) QKV_LOADX(xB, (tt + 1) * 64);
        if (tt < 14) QKV_STAGEW(b2, (tt + 2) * 64);
        QKV_COMPUTE(b0, xA);

        if (tt < 14) asm volatile("s_waitcnt vmcnt(3)" ::: "memory");
        else         asm volatile("s_waitcnt vmcnt(0)" ::: "memory");
        __builtin_amdgcn_s_barrier();
        if (tt < 14) QKV_LOADX(xA, (tt + 2) * 64);
        if (tt < 13) QKV_STAGEW(b0, (tt + 3) * 64);
        QKV_COMPUTE(b1, xB);

        b0 = b2;
    }
#undef QKV_STAGEW
#undef QKV_LOADX
#undef QKV_COMPUTE

    #pragma unroll
    for (int z = 0; z < 2; z++) {
        unsigned short* out = (z == 0) ? Qb : Kb;
        const float* bias = (z == 0) ? bq : bk;
        const float qs = (z == 0) ? CK : 1.0f;
        #pragma unroll
        for (int i = 0; i < 4; i++) {
            int oc = OC0 + i * 16 + quad * 4;
            float4 bv4 = *(const float4*)&bias[oc];
            #pragma unroll
            for (int j = 0; j < 2; j++) {
                int row = R0 + w * 32 + j * 16 + l15;
                unsigned short t4[4];
                t4[0] = f2bf_rne((acc[z][i][j][0] + bv4.x) * qs);
                t4[1] = f2bf_rne((acc[z][i][j][1] + bv4.y) * qs);
                t4[2] = f2bf_rne((acc[z][i][j][2] + bv4.z) * qs);
                t4[3] = f2bf_rne((acc[z][i][j][3] + bv4.w) * qs);
                *(uint2*)(out + (size_t)row * DMODEL + oc) = *(uint2*)t4;
            }
        }
    }
    {
        const int b = R0 >> 11;
        const int sbase = (R0 & 2047) + w * 32;
        #pragma unroll
        for (int i = 0; i < 4; i++) {
            int oc = OC0 + i * 16 + l15;
            float bvv = bv[oc];
            #pragma unroll
            for (int j = 0; j < 2; j++) {
                int sq = sbase + j * 16 + quad * 4;
                unsigned short t4[4];
                t4[0] = f2bf_rne(acc[2][i][j][0] + bvv);
                t4[1] = f2bf_rne(acc[2][i][j][1] + bvv);
                t4[2] = f2bf_rne(acc[2][i][j][2] + bvv);
                t4[3] = f2bf_rne(acc[2][i][j][3] + bvv);
                *(uint2*)(Vtb + (size_t)(b * DMODEL + oc) * S_LEN + sq) = *(uint2*)t4;
            }
        }
    }
}

// ---------------------------------------------------------------------------
// Kernel 2 (R16/R8 REVERT): flash attention, q-tile 256 x KVBLK=128.
//   R9's KVBLK=256 was a ~4 us regression (longer staging bursts between
//   full-drain barriers cost more than halved barrier count saved).
//   Reverted to the R8-measured 253.8-total config, byte-identical.
// ---------------------------------------------------------------------------
__global__ __launch_bounds__(512, 4) void flash_attn_mfma(
    const unsigned short* __restrict__ Qg,   // [B*S,1024] bf16, pre-scaled by CK
    const unsigned short* __restrict__ Kg,   // [B*S,1024] bf16
    const unsigned short* __restrict__ Vtg,  // [B,H,64,S] bf16
    unsigned short* __restrict__ ctxb)       // [B*S,1024] bf16
{
    __shared__ __align__(16) unsigned short Ks[16 * 512];  // 16 KB
    __shared__ __align__(16) unsigned short Vs[16 * 512];  // 16 KB
    __shared__ __align__(16) unsigned short Ps[16 * 512];  // 16 KB

    const int tid  = threadIdx.x;
    const int lane = tid & 63, w = tid >> 6;   // w 0..7
    const int quad = lane >> 4, l15 = lane & 15;

    // ---- XCD swizzle: 512 blocks; all 8 q-blocks of (b,h) on XCD bh%8 ----
    const int lin = blockIdx.x;            // 0..511
    const int xcd = lin & 7;
    const int s   = lin >> 3;              // 0..63
    const int bh  = xcd + 8 * (s >> 3);    // 0..63, bh%8 == xcd
    const int qblk = s & 7;                // 0..7
    const int b = bh >> 4, h = bh & 15;
    const int r0 = qblk * 256;

    bf16x8 qf[2][2];
    #pragma unroll
    for (int nt = 0; nt < 2; nt++)
        #pragma unroll
        for (int ds = 0; ds < 2; ds++)
            qf[nt][ds] = *(const bf16x8*)(Qg +
                (size_t)(b * S_LEN + r0 + w * 32 + nt * 16 + l15) * DMODEL +
                h * HD + ds * 32 + quad * 8);

    const int sw = w & 3;
    const unsigned short* gK = Kg +
        (size_t)(b * S_LEN + sw * 32 + l15) * DMODEL + h * HD + quad * 8;
    const unsigned short* gV = Vtg +
        ((size_t)(bh * HD + sw * 16 + l15)) * S_LEN + quad * 8;

    f32x4 O[2][4], lsum[2];
    #pragma unroll
    for (int rt = 0; rt < 2; rt++) {
        #pragma unroll
        for (int c = 0; c < 4; c++) lsum[rt][c] = 0.f;
        #pragma unroll
        for (int dt = 0; dt < 4; dt++)
            #pragma unroll
            for (int c = 0; c < 4; c++) O[rt][dt][c] = 0.f;
    }

    f32x4 zero4;
    #pragma unroll
    for (int c = 0; c < 4; c++) zero4[c] = 0.f;
    bf16x8 ones;
    #pragma unroll
    for (int c = 0; c < 8; c++) ones[c] = (short)0x3F80;   // bf16 1.0

    for (int st = 0; st < S_LEN / 128; st++) {
        __syncthreads();
        if (w < 4) {
            gld16(Ks + (w * 4 + 0) * 512, gK);
            gld16(Ks + (w * 4 + 1) * 512, gK + 32);
            gld16(Ks + (w * 4 + 2) * 512, gK + (size_t)16 * DMODEL);
            gld16(Ks + (w * 4 + 3) * 512, gK + (size_t)16 * DMODEL + 32);
            gK += (size_t)128 * DMODEL;
        } else {
            gld16(Vs + (sw * 4 + 0) * 512, gV);
            gld16(Vs + (sw * 4 + 1) * 512, gV + 32);
            gld16(Vs + (sw * 4 + 2) * 512, gV + 64);
            gld16(Vs + (sw * 4 + 3) * 512, gV + 96);
            gV += 128;
        }
        __syncthreads();

        #pragma unroll
        for (int r = 0; r < 4; r++) {
            f32x4 sc[2][2];
            {
                bf16x8 kf0 = *(const bf16x8*)&Ks[((r * 2 + 0) * 2 + 0) * 512 + lane * 8];
                bf16x8 kf1 = *(const bf16x8*)&Ks[((r * 2 + 1) * 2 + 0) * 512 + lane * 8];
                sc[0][0] = __builtin_amdgcn_mfma_f32_16x16x32_bf16(kf0, qf[0][0], zero4, 0, 0, 0);
                sc[0][1] = __builtin_amdgcn_mfma_f32_16x16x32_bf16(kf0, qf[1][0], zero4, 0, 0, 0);
                sc[1][0] = __builtin_amdgcn_mfma_f32_16x16x32_bf16(kf1, qf[0][0], zero4, 0, 0, 0);
                sc[1][1] = __builtin_amdgcn_mfma_f32_16x16x32_bf16(kf1, qf[1][0], zero4, 0, 0, 0);
                kf0 = *(const bf16x8*)&Ks[((r * 2 + 0) * 2 + 1) * 512 + lane * 8];
                kf1 = *(const bf16x8*)&Ks[((r * 2 + 1) * 2 + 1) * 512 + lane * 8];
                sc[0][0] = __builtin_amdgcn_mfma_f32_16x16x32_bf16(kf0, qf[0][1], sc[0][0], 0, 0, 0);
                sc[0][1] = __builtin_amdgcn_mfma_f32_16x16x32_bf16(kf0, qf[1][1], sc[0][1], 0, 0, 0);
                sc[1][0] = __builtin_amdgcn_mfma_f32_16x16x32_bf16(kf1, qf[0][1], sc[1][0], 0, 0, 0);
                sc[1][1] = __builtin_amdgcn_mfma_f32_16x16x32_bf16(kf1, qf[1][1], sc[1][1], 0, 0, 0);
            }

            #pragma unroll
            for (int nt = 0; nt < 2; nt++) {
                #pragma unroll
                for (int mt = 0; mt < 2; mt++) {
                    unsigned u[4];
                    #pragma unroll
                    for (int c = 0; c < 4; c++)
                        u[c] = __float_as_uint(__builtin_amdgcn_exp2f(sc[mt][nt][c]));
                    uint2 pk;
                    pk.x = __builtin_amdgcn_perm(u[1], u[0], 0x07060302u);
                    pk.y = __builtin_amdgcn_perm(u[3], u[2], 0x07060302u);
                    int off = (w * 2 + nt) * 512 + (mt * 2 + (quad >> 1)) * 128 +
                              l15 * 8 + (quad & 1) * 4;
                    *(uint2*)&Ps[off] = pk;
                }
            }

            bf16x8 pf0 = *(const bf16x8*)&Ps[(w * 2 + 0) * 512 + lane * 8];
            bf16x8 pf1 = *(const bf16x8*)&Ps[(w * 2 + 1) * 512 + lane * 8];
            lsum[0] = __builtin_amdgcn_mfma_f32_16x16x32_bf16(pf0, ones, lsum[0], 0, 0, 0);
            lsum[1] = __builtin_amdgcn_mfma_f32_16x16x32_bf16(pf1, ones, lsum[1], 0, 0, 0);
            #pragma unroll
            for (int dt = 0; dt < 4; dt++) {
                bf16x8 vf = *(const bf16x8*)&Vs[(dt * 4 + r) * 512 + lane * 8];
                O[0][dt] = __builtin_amdgcn_mfma_f32_16x16x32_bf16(pf0, vf, O[0][dt], 0, 0, 0);
                O[1][dt] = __builtin_amdgcn_mfma_f32_16x16x32_bf16(pf1, vf, O[1][dt], 0, 0, 0);
            }
        }
    }

    const size_t srow = (size_t)(b * S_LEN + r0 + w * 32);
    #pragma unroll
    for (int rt = 0; rt < 2; rt++) {
        #pragma unroll
        for (int reg = 0; reg < 4; reg++) {
            float li = 1.0f / lsum[rt][reg];
            size_t rowoff = (srow + rt * 16 + quad * 4 + reg) * DMODEL + h * HD + l15;
            #pragma unroll
            for (int dt = 0; dt < 4; dt++)
                ctxb[rowoff + dt * 16] = f2bf_rne(O[rt][dt][reg] * li);
        }
    }
}

// ---------------------------------------------------------------------------
// Kernel 3: output projection v4, 8-way K-split.  512 blocks x 512 thr.
// ---------------------------------------------------------------------------
__global__ __launch_bounds__(512) void out_proj_mfma(
    const unsigned short* __restrict__ ctxb,
    const unsigned short* __restrict__ WfT,
    const float* __restrict__ bfb,
    float* __restrict__ out)
{
    __shared__ float Red[8 * 1024];   // [wave][lane][j*4+reg], 32 KB

    const int tid = threadIdx.x;
    const int lane = tid & 63, w = tid >> 6;    // w 0..7
    const int quad = lane >> 4, l15 = lane & 15;
    const int m0 = blockIdx.x * 16;

    const unsigned short* pA = ctxb + (size_t)(m0 + l15) * DMODEL + w * 128 + quad * 8;
    const unsigned short* pB = WfT + (size_t)l15 * DMODEL + w * 128 + quad * 8;

    f32x4 acc[4];
    #pragma unroll
    for (int j = 0; j < 4; j++)
        #pragma unroll
        for (int c = 0; c < 4; c++) acc[j][c] = 0.f;

    #pragma unroll
    for (int k0 = 0; k0 < 128; k0 += 32) {
        bf16x8 af = *(const bf16x8*)(pA + k0);
        #pragma unroll
        for (int j = 0; j < 4; j++) {
            bf16x8 bfr = *(const bf16x8*)(pB + (size_t)j * 16 * DMODEL + k0);
            acc[j] = __builtin_amdgcn_mfma_f32_16x16x32_bf16(af, bfr, acc[j], 0, 0, 0);
        }
    }

    #pragma unroll
    for (int j = 0; j < 4; j++)
        #pragma unroll
        for (int reg = 0; reg < 4; reg++)
            Red[w * 1024 + lane * 16 + j * 4 + reg] = acc[j][reg];
    __syncthreads();

    const int row = tid >> 5;          // 0..15
    const int c0  = (tid & 31) * 2;    // 0..62
    float2 o;
    float* op = &o.x;
    #pragma unroll
    for (int cc = 0; cc < 2; cc++) {
        int col = c0 + cc;
        int idx = ((row >> 2) * 16 + (col & 15)) * 16 + (col >> 4) * 4 + (row & 3);
        float s = 0.f;
        #pragma unroll
        for (int wv = 0; wv < 8; wv++) s += Red[wv * 1024 + idx];
        op[cc] = s + bfb[col];
    }
    *(float2*)(out + (size_t)(m0 + row) * HD + c0) = o;
}

// ---------------------------------------------------------------------------
extern "C" void kernel_launch(void* const* d_in, const int* in_sizes, int n_in,
                              void* d_out, int out_size, void* d_ws, size_t ws_size,
                              hipStream_t stream)
{
    (void)in_sizes; (void)n_in; (void)out_size; (void)ws_size;
    const float* x  = (const float*)d_in[0];
    const float* Wq = (const float*)d_in[1];
    const float* bq = (const float*)d_in[2];
    const float* Wk = (const float*)d_in[3];
    const float* bk = (const float*)d_in[4];
    const float* Wv = (const float*)d_in[5];
    const float* bv = (const float*)d_in[6];
    const float* Wf = (const float*)d_in[7];
    const float* bf = (const float*)d_in[8];
    float* out = (float*)d_out;

    char* wsb = (char*)d_ws;
    unsigned short* xb   = (unsigned short*)wsb;            // 16 MB, dead after qkv
    unsigned short* ctxb = (unsigned short*)wsb;            // reuses xb region
    unsigned short* WT   = xb + (size_t)M_TOT * DMODEL;     // 3x2 MB + WfT
    unsigned short* WfT  = WT + (size_t)3 * DMODEL * DMODEL;
    unsigned short* Qb   = (unsigned short*)(wsb + (size_t)32 * 1024 * 1024);
    unsigned short* Kb   = Qb + (size_t)M_TOT * DMODEL;
    unsigned short* Vtb  = Kb + (size_t)M_TOT * DMODEL;

    cvt_fused<<<dim3(16, 16, 8), 256, 0, stream>>>(x, Wq, Wk, Wv, Wf, xb, WT);
    qkv_fused_mfma<<<dim3(512), 512, 0, stream>>>(xb, WT, bq, bk, bv, Qb, Kb, Vtb);
    flash_attn_mfma<<<dim3(512), 512, 0, stream>>>(Qb, Kb, Vtb, ctxb);
    out_proj_mfma<<<dim3(M_TOT / 16), 512, 0, stream>>>(ctxb, WfT, bf, out);
}